// Round 1
// baseline (209.192 us; speedup 1.0000x reference)
//
#include <hip/hip_runtime.h>
#include <math.h>

// ---------------------------------------------------------------------------
// FullGaussianProjector: B=1, N=512, 3 views, 224x224 out, half-res 112x112.
// Pipeline: setup (per-gaussian consts) -> splat (per-pixel reduce over n)
//           -> 2x (blur+where) -> global mean/std normalize.
// Closed form: sum_n nw = 0.5*(S - N*wmin)/(wmax-wmin+eps) + S/(S+eps).
// ---------------------------------------------------------------------------

__device__ __forceinline__ float blk_reduce_minmax(float* red, int tid, float v, bool do_min) {
    red[tid] = v;
    __syncthreads();
    for (int s = 256; s >= 1; s >>= 1) {
        if (tid < s) {
            float a = red[tid], b = red[tid + s];
            red[tid] = do_min ? fminf(a, b) : fmaxf(a, b);
        }
        __syncthreads();
    }
    float r = red[0];
    __syncthreads();
    return r;
}

// One block, 512 threads (= N). Evolves cov3d across the 3 views exactly as
// the reference (symmetrize, +eps*I, Frobenius-normalize, invert) and stores
// per-(v,n): {A00, A01, A11, xy_x, xy_y, opacity*imp}.
__global__ __launch_bounds__(512) void setup_kernel(
    const float* __restrict__ position, const float* __restrict__ cov3d,
    const float* __restrict__ opacity, const float* __restrict__ importance,
    float* __restrict__ consts) {
    __shared__ float red[512];
    const int n = threadIdx.x;

    float c00 = cov3d[n * 9 + 0], c01 = cov3d[n * 9 + 1], c02 = cov3d[n * 9 + 2];
    float c10 = cov3d[n * 9 + 3], c11 = cov3d[n * 9 + 4], c12 = cov3d[n * 9 + 5];
    float c20 = cov3d[n * 9 + 6], c21 = cov3d[n * 9 + 7], c22 = cov3d[n * 9 + 8];
    const float p0 = position[n * 3 + 0];
    const float p1 = position[n * 3 + 1];
    const float p2 = position[n * 3 + 2];
    const float opimp = opacity[n] * fminf(fmaxf(importance[n], 0.5f), 2.0f);

    for (int v = 0; v < 3; ++v) {
        // symmetrize + EPS*I
        float s01 = 0.5f * (c01 + c10);
        float s02 = 0.5f * (c02 + c20);
        float s12 = 0.5f * (c12 + c21);
        float s00 = c00 + 1e-6f;
        float s11 = c11 + 1e-6f;
        float s22 = c22 + 1e-6f;
        // Frobenius norm over all 9 entries
        float nrm = sqrtf(s00 * s00 + s11 * s11 + s22 * s22 +
                          2.0f * (s01 * s01 + s02 * s02 + s12 * s12));
        float den = nrm + 1e-6f;  // COV_HP == 1.0
        float m00 = s00 / den, m11 = s11 / den, m22 = s22 / den;
        float m01 = s01 / den, m02 = s02 / den, m12 = s12 / den;
        // carry normalized matrix to next view iteration
        c00 = m00; c11 = m11; c22 = m22;
        c01 = m01; c10 = m01; c02 = m02; c20 = m02; c12 = m12; c21 = m12;
        // symmetric 3x3 inverse via adjugate
        float cof00 = m11 * m22 - m12 * m12;
        float cof01 = m02 * m12 - m01 * m22;
        float cof02 = m01 * m12 - m02 * m11;
        float det = m00 * cof00 + m01 * cof01 + m02 * cof02;
        float idet = 1.0f / det;
        float i00 = cof00 * idet;
        float i01 = cof01 * idet;
        float i02 = cof02 * idet;
        float i11 = (m00 * m22 - m02 * m02) * idet;
        float i12 = (m02 * m01 - m00 * m12) * idet;
        float i22 = (m00 * m11 - m01 * m01) * idet;

        float Aa, Ab, Ac, prx, pry;
        if (v == 0)      { Aa = i00; Ab = i01; Ac = i11; prx = p0; pry = p1; }
        else if (v == 1) { Aa = i00; Ab = i02; Ac = i22; prx = p0; pry = p2; }
        else             { Aa = i22; Ab = i12; Ac = i11; prx = p2; pry = p1; }
        Aa += 1e-10f;  // + eye2 * (EPS*1e-4)
        Ac += 1e-10f;

        float mnx = blk_reduce_minmax(red, n, prx, true);
        float mxx = blk_reduce_minmax(red, n, prx, false);
        float mny = blk_reduce_minmax(red, n, pry, true);
        float mxy = blk_reduce_minmax(red, n, pry, false);

        float rngx = mxx - mnx + 1e-6f;
        float mnx2 = mnx - 0.5f * rngx;
        float mxx2 = mxx + 0.5f * rngx;
        rngx = mxx2 - mnx2 + 1e-6f;
        float rngy = mxy - mny + 1e-6f;
        float mny2 = mny - 0.5f * rngy;
        float mxy2 = mxy + 0.5f * rngy;
        rngy = mxy2 - mny2 + 1e-6f;

        float xx = fminf(fmaxf((prx - mnx2) / rngx * 111.0f, 0.0f), 111.0f);
        float yy = fminf(fmaxf((pry - mny2) / rngy * 111.0f, 0.0f), 111.0f);

        float* dst = consts + (v * 512 + n) * 6;
        dst[0] = Aa; dst[1] = Ab; dst[2] = Ac;
        dst[3] = xx; dst[4] = yy; dst[5] = opimp;
    }
}

__device__ __forceinline__ float quadf(float a, float b, float c, float dx, float dy) {
    // -(delta^T A delta), A = [[a,b],[b,c]]
    return -(dx * (a * dx + b * dy) + dy * (b * dx + c * dy));
}

// One thread per full-res pixel; loop over 512 gaussians (uniform const loads).
__global__ __launch_bounds__(256) void splat_kernel(
    const float* __restrict__ consts, float* __restrict__ dm) {
    const int v = blockIdx.z;
    const int xo = blockIdx.x * 32 + threadIdx.x;
    const int yo = blockIdx.y * 8 + threadIdx.y;
    const int xh = xo >> 1, yh = yo >> 1;
    const int px = xo & 1, py = yo & 1;
    int xlo = xh - 1 + px; int xhi = min(xlo + 1, 111); xlo = max(xlo, 0);
    int ylo = yh - 1 + py; int yhi = min(ylo + 1, 111); ylo = max(ylo, 0);
    const float wxlo = px ? 0.75f : 0.25f, wxhi = 1.0f - wxlo;
    const float wylo = py ? 0.75f : 0.25f, wyhi = 1.0f - wylo;
    const float fxh = (float)xh, fyh = (float)yh;
    const float fx0 = (float)xlo, fx1 = (float)xhi;
    const float fy0 = (float)ylo, fy1 = (float)yhi;

    const float* __restrict__ cv = consts + v * 512 * 6;
    float S = 0.0f, wmn = INFINITY, wmx = -INFINITY;
    #pragma unroll 4
    for (int n = 0; n < 512; ++n) {
        const float a  = cv[0];
        const float b  = cv[1];
        const float c  = cv[2];
        const float xx = cv[3];
        const float yy = cv[4];
        const float op = cv[5];
        cv += 6;
        const float dxh = fxh - xx, dyh = fyh - yy;
        float w = 0.0f;
        if (sqrtf(dxh * dxh + dyh * dyh) < 20.0f) {
            float dx0 = fx0 - xx, dx1 = fx1 - xx;
            float dy0 = fy0 - yy, dy1 = fy1 - yy;
            float e00 = quadf(a, b, c, dx0, dy0);
            float e01 = quadf(a, b, c, dx1, dy0);
            float e10 = quadf(a, b, c, dx0, dy1);
            float e11 = quadf(a, b, c, dx1, dy1);
            float bil = wylo * (wxlo * e00 + wxhi * e01) + wyhi * (wxlo * e10 + wxhi * e11);
            bil = fminf(fmaxf(bil, -20.0f), 0.0f);
            w = op * __expf(bil);
        }
        S += w;
        wmn = fminf(wmn, w);
        wmx = fmaxf(wmx, w);
    }
    float dmv = 0.5f * (S - 512.0f * wmn) / (wmx - wmn + 1e-6f) + S / (S + 1e-6f);
    dm[(v * 224 + yo) * 224 + xo] = dmv;
}

// blur (7-tap separable gaussian, zero pad, vertical then horizontal) + where.
__global__ __launch_bounds__(256) void blur_where_kernel(
    const float* __restrict__ in, float* __restrict__ out) {
    const int idx = blockIdx.x * 256 + threadIdx.x;
    if (idx >= 3 * 224 * 224) return;
    const int x = idx % 224;
    const int y = (idx / 224) % 224;
    const float* p = in + (idx - y * 224 - x);  // channel base
    const float kw[7] = {0.00443305f, 0.05400558f, 0.24203623f, 0.39905030f,
                         0.24203623f, 0.05400558f, 0.00443305f};
    const float centre = in[idx];
    float acc = 0.0f;
    for (int j = -3; j <= 3; ++j) {
        int xj = x + j;
        if (xj < 0 || xj > 223) continue;
        float s = 0.0f;
        for (int i = -3; i <= 3; ++i) {
            int yi = y + i;
            if (yi < 0 || yi > 223) continue;
            s += kw[i + 3] * p[yi * 224 + xj];
        }
        acc += kw[j + 3] * s;
    }
    out[idx] = centre > 1e-6f ? centre : acc;
}

__global__ __launch_bounds__(256) void reduce_kernel(
    const float* __restrict__ d, float* __restrict__ partials) {
    __shared__ float s1[256], s2[256];
    const int tid = threadIdx.x;
    const int idx = blockIdx.x * 256 + tid;
    float x = (idx < 3 * 224 * 224) ? d[idx] : 0.0f;
    s1[tid] = x;
    s2[tid] = x * x;
    __syncthreads();
    for (int s = 128; s >= 1; s >>= 1) {
        if (tid < s) { s1[tid] += s1[tid + s]; s2[tid] += s2[tid + s]; }
        __syncthreads();
    }
    if (tid == 0) {
        partials[blockIdx.x] = s1[0];
        partials[588 + blockIdx.x] = s2[0];
    }
}

__global__ __launch_bounds__(256) void finalize_kernel(
    const float* __restrict__ partials, float* __restrict__ stats) {
    __shared__ double s1[256], s2[256];
    const int tid = threadIdx.x;
    double a = 0.0, b = 0.0;
    for (int i = tid; i < 588; i += 256) {
        a += (double)partials[i];
        b += (double)partials[588 + i];
    }
    s1[tid] = a;
    s2[tid] = b;
    __syncthreads();
    for (int s = 128; s >= 1; s >>= 1) {
        if (tid < s) { s1[tid] += s1[tid + s]; s2[tid] += s2[tid + s]; }
        __syncthreads();
    }
    if (tid == 0) {
        const double M = 150528.0;
        double mean = s1[0] / M;
        double var = (s2[0] - M * mean * mean) / (M - 1.0);
        double sd = sqrt(var > 0.0 ? var : 0.0);
        stats[0] = (float)mean;
        stats[1] = (float)sd;
    }
}

__global__ __launch_bounds__(256) void normalize_kernel(
    const float* __restrict__ d, const float* __restrict__ stats,
    float* __restrict__ out) {
    const int idx = blockIdx.x * 256 + threadIdx.x;
    if (idx >= 3 * 224 * 224) return;
    out[idx] = (d[idx] - stats[0]) / (stats[1] + 1e-6f);
}

extern "C" void kernel_launch(void* const* d_in, const int* in_sizes, int n_in,
                              void* d_out, int out_size, void* d_ws, size_t ws_size,
                              hipStream_t stream) {
    const float* position   = (const float*)d_in[0];  // (1,512,3)
    const float* cov3d      = (const float*)d_in[1];  // (1,512,3,3)
    const float* opacity    = (const float*)d_in[2];  // (1,512)
    const float* importance = (const float*)d_in[3];  // (1,1000)
    float* out = (float*)d_out;                       // (1,3,224,224)

    float* ws = (float*)d_ws;
    float* consts   = ws;                        // 3*512*6   = 9216 floats
    float* dmA      = ws + 9216;                 // 150528 floats
    float* partials = ws + 9216 + 150528;        // 1176 floats
    float* stats    = partials + 1176;           // 2 floats

    hipLaunchKernelGGL(setup_kernel, dim3(1), dim3(512), 0, stream,
                       position, cov3d, opacity, importance, consts);
    hipLaunchKernelGGL(splat_kernel, dim3(7, 28, 3), dim3(32, 8), 0, stream,
                       consts, dmA);
    // fill step 1: dmA -> out (scratch), step 2: out -> dmA
    hipLaunchKernelGGL(blur_where_kernel, dim3(588), dim3(256), 0, stream, dmA, out);
    hipLaunchKernelGGL(blur_where_kernel, dim3(588), dim3(256), 0, stream, out, dmA);
    hipLaunchKernelGGL(reduce_kernel, dim3(588), dim3(256), 0, stream, dmA, partials);
    hipLaunchKernelGGL(finalize_kernel, dim3(1), dim3(256), 0, stream, partials, stats);
    hipLaunchKernelGGL(normalize_kernel, dim3(588), dim3(256), 0, stream, dmA, stats, out);
}

// Round 2
// 174.126 us; speedup vs baseline: 1.2014x; 1.2014x over previous
//
#include <hip/hip_runtime.h>
#include <math.h>

// ---------------------------------------------------------------------------
// FullGaussianProjector: B=1, N=512, 3 views, 224x224 out, half-res 112x112.
// setup (per-gaussian consts) -> splat (tile-culled per-pixel reduce over n)
//   -> 2x (blur+where) -> global mean/std normalize.
// Closed forms:
//   sum_n nw = 0.5*(S - N*wmin)/(wmax-wmin+eps) + S/(S+eps)
//   bilinear(quadratic) = quad(Ex,Ey) - (a*Vx + c*Vy)
// ---------------------------------------------------------------------------

__device__ __forceinline__ float wave_min(float v) {
    #pragma unroll
    for (int o = 32; o >= 1; o >>= 1) v = fminf(v, __shfl_xor(v, o));
    return v;
}

// One block, 512 threads (= N). Min/max of p0,p1,p2 computed ONCE (the view
// loop's proj min/max only ever select coordinate pairs of position).
// Stores per-(v,n): {A00, 2*A01, A11, xy_x, xy_y, opacity*imp} stride 6.
__global__ __launch_bounds__(512) void setup_kernel(
    const float* __restrict__ position, const float* __restrict__ cov3d,
    const float* __restrict__ opacity, const float* __restrict__ importance,
    float* __restrict__ consts) {
    __shared__ float red[8 * 6];
    const int n = threadIdx.x;
    const int wid = n >> 6, lane = n & 63;

    float c00 = cov3d[n * 9 + 0], c01 = cov3d[n * 9 + 1], c02 = cov3d[n * 9 + 2];
    float c10 = cov3d[n * 9 + 3], c11 = cov3d[n * 9 + 4], c12 = cov3d[n * 9 + 5];
    float c20 = cov3d[n * 9 + 6], c21 = cov3d[n * 9 + 7], c22 = cov3d[n * 9 + 8];
    const float p0 = position[n * 3 + 0];
    const float p1 = position[n * 3 + 1];
    const float p2 = position[n * 3 + 2];
    const float opimp = opacity[n] * fminf(fmaxf(importance[n], 0.5f), 2.0f);

    // 6 reduction values: min(p0), min(-p0)=-max(p0), min(p1), ... (min-only)
    {
        float vals[6] = {p0, -p0, p1, -p1, p2, -p2};
        #pragma unroll
        for (int k = 0; k < 6; ++k) {
            float r = wave_min(vals[k]);
            if (lane == 0) red[wid * 6 + k] = r;
        }
    }
    __syncthreads();
    float mn6[6];
    #pragma unroll
    for (int k = 0; k < 6; ++k) {
        float r = red[k];
        #pragma unroll
        for (int w = 1; w < 8; ++w) r = fminf(r, red[w * 6 + k]);
        mn6[k] = r;
    }
    const float pmn[3] = {mn6[0], mn6[2], mn6[4]};
    const float pmx[3] = {-mn6[1], -mn6[3], -mn6[5]};

    for (int v = 0; v < 3; ++v) {
        // symmetrize + EPS*I
        float s01 = 0.5f * (c01 + c10);
        float s02 = 0.5f * (c02 + c20);
        float s12 = 0.5f * (c12 + c21);
        float s00 = c00 + 1e-6f;
        float s11 = c11 + 1e-6f;
        float s22 = c22 + 1e-6f;
        float nrm = sqrtf(s00 * s00 + s11 * s11 + s22 * s22 +
                          2.0f * (s01 * s01 + s02 * s02 + s12 * s12));
        float den = nrm + 1e-6f;
        float m00 = s00 / den, m11 = s11 / den, m22 = s22 / den;
        float m01 = s01 / den, m02 = s02 / den, m12 = s12 / den;
        c00 = m00; c11 = m11; c22 = m22;
        c01 = m01; c10 = m01; c02 = m02; c20 = m02; c12 = m12; c21 = m12;
        // symmetric 3x3 inverse via adjugate
        float cof00 = m11 * m22 - m12 * m12;
        float cof01 = m02 * m12 - m01 * m22;
        float cof02 = m01 * m12 - m02 * m11;
        float det = m00 * cof00 + m01 * cof01 + m02 * cof02;
        float idet = 1.0f / det;
        float i00 = cof00 * idet;
        float i01 = cof01 * idet;
        float i02 = cof02 * idet;
        float i11 = (m00 * m22 - m02 * m02) * idet;
        float i12 = (m02 * m01 - m00 * m12) * idet;
        float i22 = (m00 * m11 - m01 * m01) * idet;

        float Aa, Ab, Ac, prx, pry;
        int ix, iy;
        if (v == 0)      { Aa = i00; Ab = i01; Ac = i11; prx = p0; pry = p1; ix = 0; iy = 1; }
        else if (v == 1) { Aa = i00; Ab = i02; Ac = i22; prx = p0; pry = p2; ix = 0; iy = 2; }
        else             { Aa = i22; Ab = i12; Ac = i11; prx = p2; pry = p1; ix = 2; iy = 1; }
        Aa += 1e-10f;  // + eye2 * (EPS*1e-4)
        Ac += 1e-10f;

        float mnx = pmn[ix], mxx = pmx[ix], mny = pmn[iy], mxy = pmx[iy];
        float rngx = mxx - mnx + 1e-6f;
        float mnx2 = mnx - 0.5f * rngx;
        float mxx2 = mxx + 0.5f * rngx;
        rngx = mxx2 - mnx2 + 1e-6f;
        float rngy = mxy - mny + 1e-6f;
        float mny2 = mny - 0.5f * rngy;
        float mxy2 = mxy + 0.5f * rngy;
        rngy = mxy2 - mny2 + 1e-6f;

        float xx = fminf(fmaxf((prx - mnx2) / rngx * 111.0f, 0.0f), 111.0f);
        float yy = fminf(fmaxf((pry - mny2) / rngy * 111.0f, 0.0f), 111.0f);

        float* dst = consts + (v * 512 + n) * 6;
        dst[0] = Aa; dst[1] = 2.0f * Ab; dst[2] = Ac;
        dst[3] = xx; dst[4] = yy; dst[5] = opimp;
    }
}

// Tile-culled splat. Block = 32x8 full-res pixels. Phase 1: compact gaussians
// whose half-res bbox distance < 20 into LDS (stride 8 floats -> 2x b128).
// Phase 2: per-pixel loop over the compacted list.
__global__ __launch_bounds__(256) void splat_kernel(
    const float* __restrict__ consts, float* __restrict__ dm) {
    __shared__ float ls[512 * 8];
    __shared__ int cnt;
    const int v = blockIdx.z;
    const int tx0 = blockIdx.x * 32, ty0 = blockIdx.y * 8;
    const int tid = threadIdx.y * 32 + threadIdx.x;
    // half-res bbox of this tile's pixels
    const float bx0 = (float)(tx0 >> 1), bx1 = (float)((tx0 + 31) >> 1);
    const float by0 = (float)(ty0 >> 1), by1 = (float)((ty0 + 7) >> 1);

    if (tid == 0) cnt = 0;
    __syncthreads();
    const float* __restrict__ cv = consts + v * 512 * 6;
    for (int n = tid; n < 512; n += 256) {
        const float xx = cv[n * 6 + 3], yy = cv[n * 6 + 4];
        float dx = fmaxf(fmaxf(bx0 - xx, xx - bx1), 0.0f);
        float dy = fmaxf(fmaxf(by0 - yy, yy - by1), 0.0f);
        if (sqrtf(dx * dx + dy * dy) < 20.001f) {  // conservative superset
            int slot = atomicAdd(&cnt, 1);
            #pragma unroll
            for (int k = 0; k < 6; ++k) ls[slot * 8 + k] = cv[n * 6 + k];
        }
    }
    __syncthreads();
    const int len = cnt;

    // per-pixel constants
    const int xo = tx0 + threadIdx.x;
    const int yo = ty0 + threadIdx.y;
    const int xh = xo >> 1, yh = yo >> 1;
    const int px = xo & 1, py = yo & 1;
    int xlo = xh - 1 + px; int xhi = min(xlo + 1, 111); xlo = max(xlo, 0);
    int ylo = yh - 1 + py; int yhi = min(ylo + 1, 111); ylo = max(ylo, 0);
    const float wxlo = px ? 0.75f : 0.25f, wxhi = 1.0f - wxlo;
    const float wylo = py ? 0.75f : 0.25f, wyhi = 1.0f - wylo;
    const float fx0 = (float)xlo, fx1 = (float)xhi;
    const float fy0 = (float)ylo, fy1 = (float)yhi;
    const float ex = wxlo * fx0 + wxhi * fx1;       // E[x]
    const float ey = wylo * fy0 + wyhi * fy1;       // E[y]
    const float Vx = wxlo * wxhi * (fx1 - fx0) * (fx1 - fx0);
    const float Vy = wylo * wyhi * (fy1 - fy0) * (fy1 - fy0);
    const float fxh = (float)xh, fyh = (float)yh;

    float S = 0.0f;
    float wmn = (len < 512) ? 0.0f : INFINITY;
    float wmx = (len < 512) ? 0.0f : -INFINITY;
    for (int i = 0; i < len; ++i) {
        const float a  = ls[i * 8 + 0];
        const float b2 = ls[i * 8 + 1];
        const float c  = ls[i * 8 + 2];
        const float xx = ls[i * 8 + 3];
        const float yy = ls[i * 8 + 4];
        const float op = ls[i * 8 + 5];
        const float dxh = fxh - xx, dyh = fyh - yy;
        float w = 0.0f;
        if (sqrtf(dxh * dxh + dyh * dyh) < 20.0f) {
            const float dx = ex - xx, dy = ey - yy;
            float q = dx * (a * dx + b2 * dy) + c * dy * dy;
            float bil = -(q + a * Vx + c * Vy);
            bil = fminf(fmaxf(bil, -20.0f), 0.0f);
            w = op * __expf(bil);
        }
        S += w;
        wmn = fminf(wmn, w);
        wmx = fmaxf(wmx, w);
    }
    float dmv = 0.5f * (S - 512.0f * wmn) / (wmx - wmn + 1e-6f) + S / (S + 1e-6f);
    dm[(v * 224 + yo) * 224 + xo] = dmv;
}

// blur (7-tap separable gaussian, zero pad, vertical then horizontal) + where.
__global__ __launch_bounds__(256) void blur_where_kernel(
    const float* __restrict__ in, float* __restrict__ out) {
    const int idx = blockIdx.x * 256 + threadIdx.x;
    if (idx >= 3 * 224 * 224) return;
    const int x = idx % 224;
    const int y = (idx / 224) % 224;
    const float* p = in + (idx - y * 224 - x);  // channel base
    const float kw[7] = {0.00443305f, 0.05400558f, 0.24203623f, 0.39905030f,
                         0.24203623f, 0.05400558f, 0.00443305f};
    const float centre = in[idx];
    float acc = 0.0f;
    for (int j = -3; j <= 3; ++j) {
        int xj = x + j;
        if (xj < 0 || xj > 223) continue;
        float s = 0.0f;
        for (int i = -3; i <= 3; ++i) {
            int yi = y + i;
            if (yi < 0 || yi > 223) continue;
            s += kw[i + 3] * p[yi * 224 + xj];
        }
        acc += kw[j + 3] * s;
    }
    out[idx] = centre > 1e-6f ? centre : acc;
}

__global__ __launch_bounds__(256) void reduce_kernel(
    const float* __restrict__ d, float* __restrict__ partials) {
    __shared__ float s1[256], s2[256];
    const int tid = threadIdx.x;
    const int idx = blockIdx.x * 256 + tid;
    float x = (idx < 3 * 224 * 224) ? d[idx] : 0.0f;
    s1[tid] = x;
    s2[tid] = x * x;
    __syncthreads();
    for (int s = 128; s >= 1; s >>= 1) {
        if (tid < s) { s1[tid] += s1[tid + s]; s2[tid] += s2[tid + s]; }
        __syncthreads();
    }
    if (tid == 0) {
        partials[blockIdx.x] = s1[0];
        partials[588 + blockIdx.x] = s2[0];
    }
}

__global__ __launch_bounds__(256) void finalize_kernel(
    const float* __restrict__ partials, float* __restrict__ stats) {
    __shared__ double s1[256], s2[256];
    const int tid = threadIdx.x;
    double a = 0.0, b = 0.0;
    for (int i = tid; i < 588; i += 256) {
        a += (double)partials[i];
        b += (double)partials[588 + i];
    }
    s1[tid] = a;
    s2[tid] = b;
    __syncthreads();
    for (int s = 128; s >= 1; s >>= 1) {
        if (tid < s) { s1[tid] += s1[tid + s]; s2[tid] += s2[tid + s]; }
        __syncthreads();
    }
    if (tid == 0) {
        const double M = 150528.0;
        double mean = s1[0] / M;
        double var = (s2[0] - M * mean * mean) / (M - 1.0);
        double sd = sqrt(var > 0.0 ? var : 0.0);
        stats[0] = (float)mean;
        stats[1] = (float)sd;
    }
}

__global__ __launch_bounds__(256) void normalize_kernel(
    const float* __restrict__ d, const float* __restrict__ stats,
    float* __restrict__ out) {
    const int idx = blockIdx.x * 256 + threadIdx.x;
    if (idx >= 3 * 224 * 224) return;
    out[idx] = (d[idx] - stats[0]) / (stats[1] + 1e-6f);
}

extern "C" void kernel_launch(void* const* d_in, const int* in_sizes, int n_in,
                              void* d_out, int out_size, void* d_ws, size_t ws_size,
                              hipStream_t stream) {
    const float* position   = (const float*)d_in[0];  // (1,512,3)
    const float* cov3d      = (const float*)d_in[1];  // (1,512,3,3)
    const float* opacity    = (const float*)d_in[2];  // (1,512)
    const float* importance = (const float*)d_in[3];  // (1,1000)
    float* out = (float*)d_out;                       // (1,3,224,224)

    float* ws = (float*)d_ws;
    float* consts   = ws;                        // 3*512*6   = 9216 floats
    float* dmA      = ws + 9216;                 // 150528 floats
    float* partials = ws + 9216 + 150528;        // 1176 floats
    float* stats    = partials + 1176;           // 2 floats

    hipLaunchKernelGGL(setup_kernel, dim3(1), dim3(512), 0, stream,
                       position, cov3d, opacity, importance, consts);
    hipLaunchKernelGGL(splat_kernel, dim3(7, 28, 3), dim3(32, 8), 0, stream,
                       consts, dmA);
    // fill step 1: dmA -> out (scratch), step 2: out -> dmA
    hipLaunchKernelGGL(blur_where_kernel, dim3(588), dim3(256), 0, stream, dmA, out);
    hipLaunchKernelGGL(blur_where_kernel, dim3(588), dim3(256), 0, stream, out, dmA);
    hipLaunchKernelGGL(reduce_kernel, dim3(588), dim3(256), 0, stream, dmA, partials);
    hipLaunchKernelGGL(finalize_kernel, dim3(1), dim3(256), 0, stream, partials, stats);
    hipLaunchKernelGGL(normalize_kernel, dim3(588), dim3(256), 0, stream, dmA, stats, out);
}

// Round 3
// 130.265 us; speedup vs baseline: 1.6059x; 1.3367x over previous
//
#include <hip/hip_runtime.h>
#include <math.h>

// ---------------------------------------------------------------------------
// FullGaussianProjector: B=1, N=512, 3 views, 224x224 out, half-res 112x112.
// memset(acc) -> setup -> splat (tile-culled, pair-batched LDS loop)
//   -> fused blur+where x2 + stats partials -> normalize (inline finalize).
// Closed forms:
//   sum_n nw = 0.5*(S - N*wmin)/(wmax-wmin+eps) + S/(S+eps)
//   bilinear(quadratic) = quad(Ex,Ey) - (a*Vx + c*Vy)
// ---------------------------------------------------------------------------

__device__ __forceinline__ float wave_min(float v) {
    #pragma unroll
    for (int o = 32; o >= 1; o >>= 1) v = fminf(v, __shfl_xor(v, o));
    return v;
}

// One block, 512 threads (= N). Min/max of p0,p1,p2 computed ONCE.
// Stores per-(v,n) stride 8: {A00, 2*A01, A11, xy_x, xy_y, opacity*imp, 0, 0}.
__global__ __launch_bounds__(512) void setup_kernel(
    const float* __restrict__ position, const float* __restrict__ cov3d,
    const float* __restrict__ opacity, const float* __restrict__ importance,
    float* __restrict__ consts) {
    __shared__ float red[8 * 6];
    const int n = threadIdx.x;
    const int wid = n >> 6, lane = n & 63;

    float c00 = cov3d[n * 9 + 0], c01 = cov3d[n * 9 + 1], c02 = cov3d[n * 9 + 2];
    float c10 = cov3d[n * 9 + 3], c11 = cov3d[n * 9 + 4], c12 = cov3d[n * 9 + 5];
    float c20 = cov3d[n * 9 + 6], c21 = cov3d[n * 9 + 7], c22 = cov3d[n * 9 + 8];
    const float p0 = position[n * 3 + 0];
    const float p1 = position[n * 3 + 1];
    const float p2 = position[n * 3 + 2];
    const float opimp = opacity[n] * fminf(fmaxf(importance[n], 0.5f), 2.0f);

    {
        float vals[6] = {p0, -p0, p1, -p1, p2, -p2};
        #pragma unroll
        for (int k = 0; k < 6; ++k) {
            float r = wave_min(vals[k]);
            if (lane == 0) red[wid * 6 + k] = r;
        }
    }
    __syncthreads();
    float mn6[6];
    #pragma unroll
    for (int k = 0; k < 6; ++k) {
        float r = red[k];
        #pragma unroll
        for (int w = 1; w < 8; ++w) r = fminf(r, red[w * 6 + k]);
        mn6[k] = r;
    }
    const float pmn[3] = {mn6[0], mn6[2], mn6[4]};
    const float pmx[3] = {-mn6[1], -mn6[3], -mn6[5]};

    for (int v = 0; v < 3; ++v) {
        float s01 = 0.5f * (c01 + c10);
        float s02 = 0.5f * (c02 + c20);
        float s12 = 0.5f * (c12 + c21);
        float s00 = c00 + 1e-6f;
        float s11 = c11 + 1e-6f;
        float s22 = c22 + 1e-6f;
        float nrm = sqrtf(s00 * s00 + s11 * s11 + s22 * s22 +
                          2.0f * (s01 * s01 + s02 * s02 + s12 * s12));
        float den = nrm + 1e-6f;
        float m00 = s00 / den, m11 = s11 / den, m22 = s22 / den;
        float m01 = s01 / den, m02 = s02 / den, m12 = s12 / den;
        c00 = m00; c11 = m11; c22 = m22;
        c01 = m01; c10 = m01; c02 = m02; c20 = m02; c12 = m12; c21 = m12;
        float cof00 = m11 * m22 - m12 * m12;
        float cof01 = m02 * m12 - m01 * m22;
        float cof02 = m01 * m12 - m02 * m11;
        float det = m00 * cof00 + m01 * cof01 + m02 * cof02;
        float idet = 1.0f / det;
        float i00 = cof00 * idet;
        float i01 = cof01 * idet;
        float i02 = cof02 * idet;
        float i11 = (m00 * m22 - m02 * m02) * idet;
        float i12 = (m02 * m01 - m00 * m12) * idet;
        float i22 = (m00 * m11 - m01 * m01) * idet;

        float Aa, Ab, Ac, prx, pry;
        int ix, iy;
        if (v == 0)      { Aa = i00; Ab = i01; Ac = i11; prx = p0; pry = p1; ix = 0; iy = 1; }
        else if (v == 1) { Aa = i00; Ab = i02; Ac = i22; prx = p0; pry = p2; ix = 0; iy = 2; }
        else             { Aa = i22; Ab = i12; Ac = i11; prx = p2; pry = p1; ix = 2; iy = 1; }
        Aa += 1e-10f;
        Ac += 1e-10f;

        float mnx = pmn[ix], mxx = pmx[ix], mny = pmn[iy], mxy = pmx[iy];
        float rngx = mxx - mnx + 1e-6f;
        float mnx2 = mnx - 0.5f * rngx;
        float mxx2 = mxx + 0.5f * rngx;
        rngx = mxx2 - mnx2 + 1e-6f;
        float rngy = mxy - mny + 1e-6f;
        float mny2 = mny - 0.5f * rngy;
        float mxy2 = mxy + 0.5f * rngy;
        rngy = mxy2 - mny2 + 1e-6f;

        float xx = fminf(fmaxf((prx - mnx2) / rngx * 111.0f, 0.0f), 111.0f);
        float yy = fminf(fmaxf((pry - mny2) / rngy * 111.0f, 0.0f), 111.0f);

        float* dst = consts + (v * 512 + n) * 8;
        dst[0] = Aa; dst[1] = 2.0f * Ab; dst[2] = Ac;
        dst[3] = xx; dst[4] = yy; dst[5] = opimp;
        dst[6] = 0.0f; dst[7] = 0.0f;
    }
}

// Tile-culled splat. Block = 32x8 pixels. Phase 1: wave-ballot compaction of
// gaussians with bbox-dist^2 < 400 into LDS (stride 8 = 2x float4).
// Phase 2: pair-batched per-pixel loop (4x ds_read_b128 in flight).
__global__ __launch_bounds__(256) void splat_kernel(
    const float* __restrict__ consts, float* __restrict__ dm) {
    __shared__ float ls[512 * 8];
    __shared__ int cnt;
    const int v = blockIdx.z;
    const int tx0 = blockIdx.x * 32, ty0 = blockIdx.y * 8;
    const int tid = threadIdx.y * 32 + threadIdx.x;
    const int lane = tid & 63;
    const float bx0 = (float)(tx0 >> 1), bx1 = (float)((tx0 + 31) >> 1);
    const float by0 = (float)(ty0 >> 1), by1 = (float)((ty0 + 7) >> 1);

    if (tid == 0) cnt = 0;
    __syncthreads();
    const float4* __restrict__ cvv = (const float4*)(consts + v * 512 * 8);
    #pragma unroll
    for (int t = 0; t < 2; ++t) {
        const int n = tid + t * 256;
        float4 g0 = cvv[2 * n];
        float4 g1 = cvv[2 * n + 1];
        const float xx = g0.w, yy = g1.x;
        float dx = fmaxf(fmaxf(bx0 - xx, xx - bx1), 0.0f);
        float dy = fmaxf(fmaxf(by0 - yy, yy - by1), 0.0f);
        bool pass = (dx * dx + dy * dy) < 400.01f;  // conservative superset
        unsigned long long m = __ballot(pass);
        int base = 0;
        if (lane == 0) base = atomicAdd(&cnt, __popcll(m));
        base = __shfl(base, 0);
        if (pass) {
            int slot = base + __popcll(m & ((1ull << lane) - 1ull));
            float4* d = (float4*)&ls[slot * 8];
            d[0] = g0; d[1] = g1;
        }
    }
    __syncthreads();
    if (tid == 0 && (cnt & 1)) {  // pad to even with a no-op gaussian
        float* d = &ls[cnt * 8];
        d[0] = 1.0f; d[1] = 0.0f; d[2] = 1.0f;
        d[3] = 1e9f; d[4] = 1e9f; d[5] = 0.0f; d[6] = 0.0f; d[7] = 0.0f;
    }
    __syncthreads();
    const int len = cnt;
    const int npairs = (len + 1) & ~1;

    const int xo = tx0 + threadIdx.x;
    const int yo = ty0 + threadIdx.y;
    const int xh = xo >> 1, yh = yo >> 1;
    const int px = xo & 1, py = yo & 1;
    int xlo = xh - 1 + px; int xhi = min(xlo + 1, 111); xlo = max(xlo, 0);
    int ylo = yh - 1 + py; int yhi = min(ylo + 1, 111); ylo = max(ylo, 0);
    const float wxlo = px ? 0.75f : 0.25f, wxhi = 1.0f - wxlo;
    const float wylo = py ? 0.75f : 0.25f, wyhi = 1.0f - wylo;
    const float fx0 = (float)xlo, fx1 = (float)xhi;
    const float fy0 = (float)ylo, fy1 = (float)yhi;
    const float ex = wxlo * fx0 + wxhi * fx1;
    const float ey = wylo * fy0 + wyhi * fy1;
    const float Vx = wxlo * wxhi * (fx1 - fx0) * (fx1 - fx0);
    const float Vy = wylo * wyhi * (fy1 - fy0) * (fy1 - fy0);
    const float fxh = (float)xh, fyh = (float)yh;

    float S = 0.0f;
    float wmn = (len < 512) ? 0.0f : INFINITY;
    float wmx = (len < 512) ? 0.0f : -INFINITY;
    const float4* lsv = (const float4*)ls;
    for (int i = 0; i < npairs; i += 2) {
        float4 g0a = lsv[2 * i + 0];
        float4 g0b = lsv[2 * i + 1];
        float4 g1a = lsv[2 * i + 2];
        float4 g1b = lsv[2 * i + 3];
        // gaussian i
        {
            const float dxh = fxh - g0a.w, dyh = fyh - g0b.x;
            float w = 0.0f;
            if (dxh * dxh + dyh * dyh < 400.0f) {
                const float dx = ex - g0a.w, dy = ey - g0b.x;
                float q = dx * (g0a.x * dx + g0a.y * dy) + g0a.z * dy * dy;
                float bil = -(q + g0a.x * Vx + g0a.z * Vy);
                bil = fminf(fmaxf(bil, -20.0f), 0.0f);
                w = g0b.y * __expf(bil);
            }
            S += w; wmn = fminf(wmn, w); wmx = fmaxf(wmx, w);
        }
        // gaussian i+1
        {
            const float dxh = fxh - g1a.w, dyh = fyh - g1b.x;
            float w = 0.0f;
            if (dxh * dxh + dyh * dyh < 400.0f) {
                const float dx = ex - g1a.w, dy = ey - g1b.x;
                float q = dx * (g1a.x * dx + g1a.y * dy) + g1a.z * dy * dy;
                float bil = -(q + g1a.x * Vx + g1a.z * Vy);
                bil = fminf(fmaxf(bil, -20.0f), 0.0f);
                w = g1b.y * __expf(bil);
            }
            S += w; wmn = fminf(wmn, w); wmx = fmaxf(wmx, w);
        }
    }
    float dmv = 0.5f * (S - 512.0f * wmn) / (wmx - wmn + 1e-6f) + S / (S + 1e-6f);
    dm[(v * 224 + yo) * 224 + xo] = dmv;
}

// Fused: d1 = where(d, blur(d)); d2 = where(d1, blur(d1)); out = d2;
// block partial sums (sum, sumsq) -> double atomicAdd.
// Tile 32x32 + halo 6 -> 44x44 LDS region. Separable vert-then-horiz, zero pad.
__global__ __launch_bounds__(256) void blur2_stats_kernel(
    const float* __restrict__ in, float* __restrict__ out,
    double* __restrict__ acc) {
    __shared__ float A[44 * 45];
    __shared__ float T[44 * 45];
    __shared__ float r1[4], r2[4];
    const int v = blockIdx.z;
    const int tx0 = blockIdx.x * 32, ty0 = blockIdx.y * 32;
    const int tid = threadIdx.x;
    const float kw[7] = {0.00443305f, 0.05400558f, 0.24203623f, 0.39905030f,
                         0.24203623f, 0.05400558f, 0.00443305f};
    const float* __restrict__ chan = in + v * 224 * 224;

    for (int idx = tid; idx < 44 * 44; idx += 256) {
        int r = idx / 44, c = idx % 44;
        int gy = ty0 - 6 + r, gx = tx0 - 6 + c;
        float val = 0.0f;
        if (gy >= 0 && gy < 224 && gx >= 0 && gx < 224) val = chan[gy * 224 + gx];
        A[r * 45 + c] = val;
    }
    __syncthreads();
    // vertical blur of d: rows 3..40, cols 0..43
    for (int idx = tid; idx < 38 * 44; idx += 256) {
        int r = 3 + idx / 44, c = idx % 44;
        float s = 0.0f;
        #pragma unroll
        for (int i = 0; i < 7; ++i) s += kw[i] * A[(r - 3 + i) * 45 + c];
        T[r * 45 + c] = s;
    }
    __syncthreads();
    // horizontal + where -> d1 (rows 3..40, cols 3..40), in-place into A
    for (int idx = tid; idx < 38 * 38; idx += 256) {
        int r = 3 + idx / 38, c = 3 + idx % 38;
        float s = 0.0f;
        #pragma unroll
        for (int j = 0; j < 7; ++j) s += kw[j] * T[r * 45 + c - 3 + j];
        float ctr = A[r * 45 + c];
        A[r * 45 + c] = ctr > 1e-6f ? ctr : s;
    }
    __syncthreads();
    // vertical blur of d1: rows 6..37, cols 3..40
    for (int idx = tid; idx < 32 * 38; idx += 256) {
        int r = 6 + idx / 38, c = 3 + idx % 38;
        float s = 0.0f;
        #pragma unroll
        for (int i = 0; i < 7; ++i) s += kw[i] * A[(r - 3 + i) * 45 + c];
        T[r * 45 + c] = s;
    }
    __syncthreads();
    // horizontal + where -> d2, write out + stats
    float ls1 = 0.0f, ls2 = 0.0f;
    for (int idx = tid; idx < 32 * 32; idx += 256) {
        int r = 6 + (idx >> 5), c = 6 + (idx & 31);
        float s = 0.0f;
        #pragma unroll
        for (int j = 0; j < 7; ++j) s += kw[j] * T[r * 45 + c - 3 + j];
        float ctr = A[r * 45 + c];
        float d2 = ctr > 1e-6f ? ctr : s;
        out[(v * 224 + ty0 + r - 6) * 224 + (tx0 + c - 6)] = d2;
        ls1 += d2; ls2 += d2 * d2;
    }
    #pragma unroll
    for (int o = 32; o >= 1; o >>= 1) {
        ls1 += __shfl_xor(ls1, o);
        ls2 += __shfl_xor(ls2, o);
    }
    if ((tid & 63) == 0) { r1[tid >> 6] = ls1; r2[tid >> 6] = ls2; }
    __syncthreads();
    if (tid == 0) {
        double s1 = (double)r1[0] + r1[1] + r1[2] + r1[3];
        double s2 = (double)r2[0] + r2[1] + r2[2] + r2[3];
        atomicAdd(acc, s1);
        atomicAdd(acc + 1, s2);
    }
}

// Finalize fused into normalize: every thread derives mean/sd from acc.
__global__ __launch_bounds__(256) void normalize_kernel(
    const double* __restrict__ acc, float* __restrict__ out) {
    const int idx = blockIdx.x * 256 + threadIdx.x;
    if (idx >= 3 * 224 * 224) return;
    const double M = 150528.0;
    double mean = acc[0] / M;
    double var = (acc[1] - M * mean * mean) / (M - 1.0);
    double sd = sqrt(var > 0.0 ? var : 0.0);
    out[idx] = (out[idx] - (float)mean) / ((float)sd + 1e-6f);
}

extern "C" void kernel_launch(void* const* d_in, const int* in_sizes, int n_in,
                              void* d_out, int out_size, void* d_ws, size_t ws_size,
                              hipStream_t stream) {
    const float* position   = (const float*)d_in[0];  // (1,512,3)
    const float* cov3d      = (const float*)d_in[1];  // (1,512,3,3)
    const float* opacity    = (const float*)d_in[2];  // (1,512)
    const float* importance = (const float*)d_in[3];  // (1,1000)
    float* out = (float*)d_out;                       // (1,3,224,224)

    double* acc   = (double*)d_ws;                    // 2 doubles (16 B)
    float* consts = (float*)d_ws + 4;                 // 3*512*8 = 12288 floats
    float* dmA    = (float*)d_ws + 4 + 12288;         // 150528 floats

    hipMemsetAsync(acc, 0, 2 * sizeof(double), stream);
    hipLaunchKernelGGL(setup_kernel, dim3(1), dim3(512), 0, stream,
                       position, cov3d, opacity, importance, consts);
    hipLaunchKernelGGL(splat_kernel, dim3(7, 28, 3), dim3(32, 8), 0, stream,
                       consts, dmA);
    hipLaunchKernelGGL(blur2_stats_kernel, dim3(7, 7, 3), dim3(256), 0, stream,
                       dmA, out, acc);
    hipLaunchKernelGGL(normalize_kernel, dim3(588), dim3(256), 0, stream,
                       acc, out);
}

// Round 4
// 99.620 us; speedup vs baseline: 2.0999x; 1.3076x over previous
//
#include <hip/hip_runtime.h>
#include <math.h>

// ---------------------------------------------------------------------------
// FullGaussianProjector: B=1, N=512, 3 views, 224x224 out, half-res 112x112.
// 3 launches:
//   splat_fused: per-block redundant setup -> tile cull/compact -> 4-replica
//                split of the list across 8 waves -> LDS merge -> dm
//   blur2_stats: 2x (separable blur + where) in LDS + per-block partial sums
//   normalize:   inline reduce of 147 partials -> (x-mean)/(sd+eps)
// Closed forms:
//   sum_n nw = 0.5*(S - N*wmin)/(wmax-wmin+eps) + S/(S+eps)
//   bilinear(quadratic) = quad(Ex,Ey) - (a*Vx + c*Vy)
// ---------------------------------------------------------------------------

__device__ __forceinline__ float wave_min(float v) {
    #pragma unroll
    for (int o = 32; o >= 1; o >>= 1) v = fminf(v, __shfl_xor(v, o));
    return v;
}

// Block: 512 threads (8 waves), tile 16x8 full-res pixels, grid (14,28,3).
__global__ __launch_bounds__(512) void splat_fused_kernel(
    const float* __restrict__ position, const float* __restrict__ cov3d,
    const float* __restrict__ opacity, const float* __restrict__ importance,
    float* __restrict__ dm) {
    __shared__ float ls[512 * 8];      // compacted gaussian list, stride 8
    __shared__ float red[8 * 6];       // cross-wave min/max scratch
    __shared__ float pS[3][128], pMn[3][128], pMx[3][128];
    __shared__ int cnt;
    const int v = blockIdx.z;
    const int tx0 = blockIdx.x * 16, ty0 = blockIdx.y * 8;
    const int tid = threadIdx.x;
    const int lane = tid & 63, wave = tid >> 6;

    // ---------------- setup (1 gaussian per thread) ----------------
    const int n = tid;
    const float p0 = position[n * 3 + 0];
    const float p1 = position[n * 3 + 1];
    const float p2 = position[n * 3 + 2];
    const float opimp = opacity[n] * fminf(fmaxf(importance[n], 0.5f), 2.0f);

    // block-wide min/max of p0,p1,p2 (as 6 mins)
    {
        float vals[6] = {p0, -p0, p1, -p1, p2, -p2};
        #pragma unroll
        for (int k = 0; k < 6; ++k) {
            float r = wave_min(vals[k]);
            if (lane == 0) red[wave * 6 + k] = r;
        }
    }
    __syncthreads();
    float mn6[6];
    #pragma unroll
    for (int k = 0; k < 6; ++k) {
        float r = red[k];
        #pragma unroll
        for (int w = 1; w < 8; ++w) r = fminf(r, red[w * 6 + k]);
        mn6[k] = r;
    }
    const float pmn[3] = {mn6[0], mn6[2], mn6[4]};
    const float pmx[3] = {-mn6[1], -mn6[3], -mn6[5]};

    float c00 = cov3d[n * 9 + 0], c01 = cov3d[n * 9 + 1], c02 = cov3d[n * 9 + 2];
    float c10 = cov3d[n * 9 + 3], c11 = cov3d[n * 9 + 4], c12 = cov3d[n * 9 + 5];
    float c20 = cov3d[n * 9 + 6], c21 = cov3d[n * 9 + 7], c22 = cov3d[n * 9 + 8];
    // normalize chain: view v uses the matrix after (v+1) normalize steps
    for (int vv = 0; vv <= v; ++vv) {
        float s01 = 0.5f * (c01 + c10);
        float s02 = 0.5f * (c02 + c20);
        float s12 = 0.5f * (c12 + c21);
        float s00 = c00 + 1e-6f;
        float s11 = c11 + 1e-6f;
        float s22 = c22 + 1e-6f;
        float nrm = sqrtf(s00 * s00 + s11 * s11 + s22 * s22 +
                          2.0f * (s01 * s01 + s02 * s02 + s12 * s12));
        float inv = 1.0f / (nrm + 1e-6f);
        c00 = s00 * inv; c11 = s11 * inv; c22 = s22 * inv;
        c01 = s01 * inv; c10 = c01; c02 = s02 * inv; c20 = c02;
        c12 = s12 * inv; c21 = c12;
    }
    // symmetric 3x3 inverse via adjugate
    float cof00 = c11 * c22 - c12 * c12;
    float cof01 = c02 * c12 - c01 * c22;
    float cof02 = c01 * c12 - c02 * c11;
    float det = c00 * cof00 + c01 * cof01 + c02 * cof02;
    float idet = 1.0f / det;
    float i00 = cof00 * idet;
    float i01 = cof01 * idet;
    float i02 = cof02 * idet;
    float i11 = (c00 * c22 - c02 * c02) * idet;
    float i12 = (c02 * c01 - c00 * c12) * idet;
    float i22 = (c00 * c11 - c01 * c01) * idet;

    float Aa, Ab, Ac, prx, pry;
    int ix, iy;
    if (v == 0)      { Aa = i00; Ab = i01; Ac = i11; prx = p0; pry = p1; ix = 0; iy = 1; }
    else if (v == 1) { Aa = i00; Ab = i02; Ac = i22; prx = p0; pry = p2; ix = 0; iy = 2; }
    else             { Aa = i22; Ab = i12; Ac = i11; prx = p2; pry = p1; ix = 2; iy = 1; }
    Aa += 1e-10f;  // + eye2 * (EPS*1e-4)
    Ac += 1e-10f;

    float mnx = pmn[ix], mxx = pmx[ix], mny = pmn[iy], mxy = pmx[iy];
    float rngx = mxx - mnx + 1e-6f;
    float mnx2 = mnx - 0.5f * rngx;
    float mxx2 = mxx + 0.5f * rngx;
    rngx = mxx2 - mnx2 + 1e-6f;
    float rngy = mxy - mny + 1e-6f;
    float mny2 = mny - 0.5f * rngy;
    float mxy2 = mxy + 0.5f * rngy;
    rngy = mxy2 - mny2 + 1e-6f;
    float gx = fminf(fmaxf((prx - mnx2) / rngx * 111.0f, 0.0f), 111.0f);
    float gy = fminf(fmaxf((pry - mny2) / rngy * 111.0f, 0.0f), 111.0f);

    // ---------------- cull + compact into LDS ----------------
    if (tid == 0) cnt = 0;
    __syncthreads();
    {
        const float bx0 = (float)(tx0 >> 1), bx1 = (float)((tx0 + 15) >> 1);
        const float by0 = (float)(ty0 >> 1), by1 = (float)((ty0 + 7) >> 1);
        float dx = fmaxf(fmaxf(bx0 - gx, gx - bx1), 0.0f);
        float dy = fmaxf(fmaxf(by0 - gy, gy - by1), 0.0f);
        bool pass = (dx * dx + dy * dy) < 400.01f;  // conservative superset
        unsigned long long m = __ballot(pass);
        int base = 0;
        if (lane == 0) base = atomicAdd(&cnt, __popcll(m));
        base = __shfl(base, 0);
        if (pass) {
            int slot = base + __popcll(m & ((1ull << lane) - 1ull));
            float4* d = (float4*)&ls[slot * 8];
            d[0] = make_float4(Aa, 2.0f * Ab, Ac, gx);
            d[1] = make_float4(gy, opimp, 0.0f, 0.0f);
        }
    }
    __syncthreads();
    const int len = cnt;
    const int npad = (len + 15) & ~15;
    if (tid < npad - len) {  // no-op pad gaussians (w = 0)
        float4* d = (float4*)&ls[(len + tid) * 8];
        d[0] = make_float4(1.0f, 0.0f, 1.0f, 1e9f);
        d[1] = make_float4(1e9f, 0.0f, 0.0f, 0.0f);
    }
    __syncthreads();

    // ---------------- per-pixel loop, 4 replicas x 2 waves ----------------
    const int r = wave >> 1;                 // replica 0..3
    const int pid = (wave & 1) * 64 + lane;  // pixel 0..127 in tile
    const int xo = tx0 + (pid & 15);
    const int yo = ty0 + (pid >> 4);
    const int xh = xo >> 1, yh = yo >> 1;
    const int px = xo & 1, py = yo & 1;
    int xlo = xh - 1 + px; int xhi = min(xlo + 1, 111); xlo = max(xlo, 0);
    int ylo = yh - 1 + py; int yhi = min(ylo + 1, 111); ylo = max(ylo, 0);
    const float wxlo = px ? 0.75f : 0.25f, wxhi = 1.0f - wxlo;
    const float wylo = py ? 0.75f : 0.25f, wyhi = 1.0f - wylo;
    const float fx0 = (float)xlo, fx1 = (float)xhi;
    const float fy0 = (float)ylo, fy1 = (float)yhi;
    const float ex = wxlo * fx0 + wxhi * fx1;
    const float ey = wylo * fy0 + wyhi * fy1;
    const float Vx = wxlo * wxhi * (fx1 - fx0) * (fx1 - fx0);
    const float Vy = wylo * wyhi * (fy1 - fy0) * (fy1 - fy0);
    const float fxh = (float)xh, fyh = (float)yh;

    float S = 0.0f, wmn = INFINITY, wmx = -INFINITY;
    const float4* lsv = (const float4*)ls;
    for (int base = r * 4; base < npad; base += 16) {
        float4 ga[4], gb[4];
        #pragma unroll
        for (int k = 0; k < 4; ++k) {
            ga[k] = lsv[2 * (base + k)];
            gb[k] = lsv[2 * (base + k) + 1];
        }
        #pragma unroll
        for (int k = 0; k < 4; ++k) {
            const float xx = ga[k].w, yy = gb[k].x;
            const float dxh = fxh - xx, dyh = fyh - yy;
            float w = 0.0f;
            if (dxh * dxh + dyh * dyh < 400.0f) {
                const float dx = ex - xx, dy = ey - yy;
                float q = dx * (ga[k].x * dx + ga[k].y * dy) + ga[k].z * dy * dy;
                float bil = -(q + ga[k].x * Vx + ga[k].z * Vy);
                bil = fminf(fmaxf(bil, -20.0f), 0.0f);
                w = gb[k].y * __expf(bil);
            }
            S += w; wmn = fminf(wmn, w); wmx = fmaxf(wmx, w);
        }
    }
    if (r > 0) { pS[r - 1][pid] = S; pMn[r - 1][pid] = wmn; pMx[r - 1][pid] = wmx; }
    __syncthreads();
    if (r == 0) {
        #pragma unroll
        for (int k = 0; k < 3; ++k) {
            S += pS[k][pid];
            wmn = fminf(wmn, pMn[k][pid]);
            wmx = fmaxf(wmx, pMx[k][pid]);
        }
        if (len < 512) { wmn = fminf(wmn, 0.0f); wmx = fmaxf(wmx, 0.0f); }
        float dmv = 0.5f * (S - 512.0f * wmn) / (wmx - wmn + 1e-6f) + S / (S + 1e-6f);
        dm[(v * 224 + yo) * 224 + xo] = dmv;
    }
}

// Fused: d1 = where(d, blur(d)); d2 = where(d1, blur(d1)); out = d2;
// per-block partial (sum, sumsq) -> partials[bid].
__global__ __launch_bounds__(256) void blur2_stats_kernel(
    const float* __restrict__ in, float* __restrict__ out,
    float2* __restrict__ partials) {
    __shared__ float A[44 * 45];
    __shared__ float T[44 * 45];
    __shared__ float r1[4], r2[4];
    const int v = blockIdx.z;
    const int tx0 = blockIdx.x * 32, ty0 = blockIdx.y * 32;
    const int tid = threadIdx.x;
    const float kw[7] = {0.00443305f, 0.05400558f, 0.24203623f, 0.39905030f,
                         0.24203623f, 0.05400558f, 0.00443305f};
    const float* __restrict__ chan = in + v * 224 * 224;

    for (int idx = tid; idx < 44 * 44; idx += 256) {
        int rr = idx / 44, c = idx % 44;
        int gyy = ty0 - 6 + rr, gxx = tx0 - 6 + c;
        float val = 0.0f;
        if (gyy >= 0 && gyy < 224 && gxx >= 0 && gxx < 224) val = chan[gyy * 224 + gxx];
        A[rr * 45 + c] = val;
    }
    __syncthreads();
    for (int idx = tid; idx < 38 * 44; idx += 256) {
        int rr = 3 + idx / 44, c = idx % 44;
        float s = 0.0f;
        #pragma unroll
        for (int i = 0; i < 7; ++i) s += kw[i] * A[(rr - 3 + i) * 45 + c];
        T[rr * 45 + c] = s;
    }
    __syncthreads();
    for (int idx = tid; idx < 38 * 38; idx += 256) {
        int rr = 3 + idx / 38, c = 3 + idx % 38;
        float s = 0.0f;
        #pragma unroll
        for (int j = 0; j < 7; ++j) s += kw[j] * T[rr * 45 + c - 3 + j];
        float ctr = A[rr * 45 + c];
        A[rr * 45 + c] = ctr > 1e-6f ? ctr : s;
    }
    __syncthreads();
    for (int idx = tid; idx < 32 * 38; idx += 256) {
        int rr = 6 + idx / 38, c = 3 + idx % 38;
        float s = 0.0f;
        #pragma unroll
        for (int i = 0; i < 7; ++i) s += kw[i] * A[(rr - 3 + i) * 45 + c];
        T[rr * 45 + c] = s;
    }
    __syncthreads();
    float ls1 = 0.0f, ls2 = 0.0f;
    for (int idx = tid; idx < 32 * 32; idx += 256) {
        int rr = 6 + (idx >> 5), c = 6 + (idx & 31);
        float s = 0.0f;
        #pragma unroll
        for (int j = 0; j < 7; ++j) s += kw[j] * T[rr * 45 + c - 3 + j];
        float ctr = A[rr * 45 + c];
        float d2 = ctr > 1e-6f ? ctr : s;
        out[(v * 224 + ty0 + rr - 6) * 224 + (tx0 + c - 6)] = d2;
        ls1 += d2; ls2 += d2 * d2;
    }
    #pragma unroll
    for (int o = 32; o >= 1; o >>= 1) {
        ls1 += __shfl_xor(ls1, o);
        ls2 += __shfl_xor(ls2, o);
    }
    if ((tid & 63) == 0) { r1[tid >> 6] = ls1; r2[tid >> 6] = ls2; }
    __syncthreads();
    if (tid == 0) {
        float s1 = r1[0] + r1[1] + r1[2] + r1[3];
        float s2 = r2[0] + r2[1] + r2[2] + r2[3];
        partials[(blockIdx.z * 7 + blockIdx.y) * 7 + blockIdx.x] = make_float2(s1, s2);
    }
}

// Inline reduce of 147 block partials (double), then normalize in place.
__global__ __launch_bounds__(256) void normalize_kernel(
    const float2* __restrict__ partials, float* __restrict__ out) {
    __shared__ double s1[256], s2[256];
    const int tid = threadIdx.x;
    double a = 0.0, b = 0.0;
    if (tid < 147) {
        float2 p = partials[tid];
        a = (double)p.x; b = (double)p.y;
    }
    s1[tid] = a; s2[tid] = b;
    __syncthreads();
    for (int s = 128; s >= 1; s >>= 1) {
        if (tid < s) { s1[tid] += s1[tid + s]; s2[tid] += s2[tid + s]; }
        __syncthreads();
    }
    const double M = 150528.0;
    double mean = s1[0] / M;
    double var = (s2[0] - M * mean * mean) / (M - 1.0);
    double sd = sqrt(var > 0.0 ? var : 0.0);
    const int idx = blockIdx.x * 256 + tid;
    if (idx < 3 * 224 * 224)
        out[idx] = (out[idx] - (float)mean) / ((float)sd + 1e-6f);
}

extern "C" void kernel_launch(void* const* d_in, const int* in_sizes, int n_in,
                              void* d_out, int out_size, void* d_ws, size_t ws_size,
                              hipStream_t stream) {
    const float* position   = (const float*)d_in[0];  // (1,512,3)
    const float* cov3d      = (const float*)d_in[1];  // (1,512,3,3)
    const float* opacity    = (const float*)d_in[2];  // (1,512)
    const float* importance = (const float*)d_in[3];  // (1,1000)
    float* out = (float*)d_out;                       // (1,3,224,224)

    float* dmA       = (float*)d_ws;                  // 150528 floats
    float2* partials = (float2*)((float*)d_ws + 150528);  // 147 float2

    hipLaunchKernelGGL(splat_fused_kernel, dim3(14, 28, 3), dim3(512), 0, stream,
                       position, cov3d, opacity, importance, dmA);
    hipLaunchKernelGGL(blur2_stats_kernel, dim3(7, 7, 3), dim3(256), 0, stream,
                       dmA, out, partials);
    hipLaunchKernelGGL(normalize_kernel, dim3(588), dim3(256), 0, stream,
                       partials, out);
}

// Round 6
// 95.070 us; speedup vs baseline: 2.2004x; 1.0479x over previous
//
#include <hip/hip_runtime.h>
#include <math.h>

// ---------------------------------------------------------------------------
// FullGaussianProjector: B=1, N=512, 3 views, 224x224 out, half-res 112x112.
// 3 launches:
//   splat_fused: per-block redundant setup -> tile cull/compact (SoA f32:
//                float4 a,2b,c,op + float2 gx,gy) -> 8-replica split across
//                8 waves (8x8-px tile) -> LDS merge -> dm.
//   blur2_stats: 2x (separable blur + where) in LDS + per-block partial sums
//                (d1 halo zeroed outside image = exact zero-pad semantics)
//   normalize:   inline reduce of 588 partials -> (x-mean)/(sd+eps)
// Closed forms:
//   sum_n nw = 0.5*(S - N*wmin)/(wmax-wmin+eps) + S/(S+eps)
//   bilinear(quadratic) = quad(Ex,Ey) - (a*Vx + c*Vy)
// NOTE (R5 lesson): a,2b,c,op must stay f32 — bf16 on the exponent path
// fails absmax (0.115 > 0.093) through the (wmax-wmin) normalization.
// ---------------------------------------------------------------------------

__device__ __forceinline__ float wave_min(float v) {
    #pragma unroll
    for (int o = 32; o >= 1; o >>= 1) v = fminf(v, __shfl_xor(v, o));
    return v;
}

// Block: 512 threads (8 waves), tile 8x8 full-res pixels, grid (28,28,3).
__global__ __launch_bounds__(512) void splat_fused_kernel(
    const float* __restrict__ position, const float* __restrict__ cov3d,
    const float* __restrict__ opacity, const float* __restrict__ importance,
    float* __restrict__ dm) {
    __shared__ float4 lsA[512];        // a, 2b, c, op
    __shared__ float2 lsB[512];        // gx, gy
    __shared__ float red[8 * 6];       // cross-wave min/max scratch
    __shared__ float pS[7][64], pMn[7][64], pMx[7][64];
    __shared__ int cnt;
    const int v = blockIdx.z;
    const int tx0 = blockIdx.x * 8, ty0 = blockIdx.y * 8;
    const int tid = threadIdx.x;
    const int lane = tid & 63, wave = tid >> 6;

    // ---------------- setup (1 gaussian per thread) ----------------
    const int n = tid;
    const float p0 = position[n * 3 + 0];
    const float p1 = position[n * 3 + 1];
    const float p2 = position[n * 3 + 2];
    const float opimp = opacity[n] * fminf(fmaxf(importance[n], 0.5f), 2.0f);

    {
        float vals[6] = {p0, -p0, p1, -p1, p2, -p2};
        #pragma unroll
        for (int k = 0; k < 6; ++k) {
            float r = wave_min(vals[k]);
            if (lane == 0) red[wave * 6 + k] = r;
        }
    }
    __syncthreads();
    float mn6[6];
    #pragma unroll
    for (int k = 0; k < 6; ++k) {
        float r = red[k];
        #pragma unroll
        for (int w = 1; w < 8; ++w) r = fminf(r, red[w * 6 + k]);
        mn6[k] = r;
    }
    const float pmn[3] = {mn6[0], mn6[2], mn6[4]};
    const float pmx[3] = {-mn6[1], -mn6[3], -mn6[5]};

    float c00 = cov3d[n * 9 + 0], c01 = cov3d[n * 9 + 1], c02 = cov3d[n * 9 + 2];
    float c10 = cov3d[n * 9 + 3], c11 = cov3d[n * 9 + 4], c12 = cov3d[n * 9 + 5];
    float c20 = cov3d[n * 9 + 6], c21 = cov3d[n * 9 + 7], c22 = cov3d[n * 9 + 8];
    for (int vv = 0; vv <= v; ++vv) {
        float s01 = 0.5f * (c01 + c10);
        float s02 = 0.5f * (c02 + c20);
        float s12 = 0.5f * (c12 + c21);
        float s00 = c00 + 1e-6f;
        float s11 = c11 + 1e-6f;
        float s22 = c22 + 1e-6f;
        float nrm = sqrtf(s00 * s00 + s11 * s11 + s22 * s22 +
                          2.0f * (s01 * s01 + s02 * s02 + s12 * s12));
        float inv = 1.0f / (nrm + 1e-6f);
        c00 = s00 * inv; c11 = s11 * inv; c22 = s22 * inv;
        c01 = s01 * inv; c10 = c01; c02 = s02 * inv; c20 = c02;
        c12 = s12 * inv; c21 = c12;
    }
    float cof00 = c11 * c22 - c12 * c12;
    float cof01 = c02 * c12 - c01 * c22;
    float cof02 = c01 * c12 - c02 * c11;
    float det = c00 * cof00 + c01 * cof01 + c02 * cof02;
    float idet = 1.0f / det;
    float i00 = cof00 * idet;
    float i01 = cof01 * idet;
    float i02 = cof02 * idet;
    float i11 = (c00 * c22 - c02 * c02) * idet;
    float i12 = (c02 * c01 - c00 * c12) * idet;
    float i22 = (c00 * c11 - c01 * c01) * idet;

    float Aa, Ab, Ac, prx, pry;
    int ix, iy;
    if (v == 0)      { Aa = i00; Ab = i01; Ac = i11; prx = p0; pry = p1; ix = 0; iy = 1; }
    else if (v == 1) { Aa = i00; Ab = i02; Ac = i22; prx = p0; pry = p2; ix = 0; iy = 2; }
    else             { Aa = i22; Ab = i12; Ac = i11; prx = p2; pry = p1; ix = 2; iy = 1; }
    Aa += 1e-10f;
    Ac += 1e-10f;

    float mnx = pmn[ix], mxx = pmx[ix], mny = pmn[iy], mxy = pmx[iy];
    float rngx = mxx - mnx + 1e-6f;
    float mnx2 = mnx - 0.5f * rngx;
    float mxx2 = mxx + 0.5f * rngx;
    rngx = mxx2 - mnx2 + 1e-6f;
    float rngy = mxy - mny + 1e-6f;
    float mny2 = mny - 0.5f * rngy;
    float mxy2 = mxy + 0.5f * rngy;
    rngy = mxy2 - mny2 + 1e-6f;
    float gx = fminf(fmaxf((prx - mnx2) / rngx * 111.0f, 0.0f), 111.0f);
    float gy = fminf(fmaxf((pry - mny2) / rngy * 111.0f, 0.0f), 111.0f);

    // ---------------- cull + compact into LDS (SoA f32) ----------------
    if (tid == 0) cnt = 0;
    __syncthreads();
    {
        const float bx0 = (float)(tx0 >> 1), bx1 = (float)((tx0 + 7) >> 1);
        const float by0 = (float)(ty0 >> 1), by1 = (float)((ty0 + 7) >> 1);
        float dx = fmaxf(fmaxf(bx0 - gx, gx - bx1), 0.0f);
        float dy = fmaxf(fmaxf(by0 - gy, gy - by1), 0.0f);
        bool pass = (dx * dx + dy * dy) < 400.01f;  // conservative superset
        unsigned long long m = __ballot(pass);
        int base = 0;
        if (lane == 0) base = atomicAdd(&cnt, __popcll(m));
        base = __shfl(base, 0);
        if (pass) {
            int slot = base + __popcll(m & ((1ull << lane) - 1ull));
            lsA[slot] = make_float4(Aa, 2.0f * Ab, Ac, opimp);
            lsB[slot] = make_float2(gx, gy);
        }
    }
    __syncthreads();
    const int len = cnt;

    const int rep = wave;            // replica 0..7, each covers all 64 px
    const int xo = tx0 + (lane & 7);
    const int yo = ty0 + (lane >> 3);

    if (len == 0) {  // uniform branch: whole block exits
        if (rep == 0) dm[(v * 224 + yo) * 224 + xo] = 0.0f;
        return;
    }

    const int npad = (len + 31) & ~31;
    if (tid < npad - len) {  // no-op pad gaussians (mask always fails -> w=0)
        lsA[len + tid] = make_float4(1.0f, 0.0f, 1.0f, 0.0f);
        lsB[len + tid] = make_float2(1e9f, 1e9f);
    }
    __syncthreads();

    // ---------------- per-pixel loop, 8 replicas x 8 waves ----------------
    const int xh = xo >> 1, yh = yo >> 1;
    const int px = xo & 1, py = yo & 1;
    int xlo = xh - 1 + px; int xhi = min(xlo + 1, 111); xlo = max(xlo, 0);
    int ylo = yh - 1 + py; int yhi = min(ylo + 1, 111); ylo = max(ylo, 0);
    const float wxlo = px ? 0.75f : 0.25f, wxhi = 1.0f - wxlo;
    const float wylo = py ? 0.75f : 0.25f, wyhi = 1.0f - wylo;
    const float fx0 = (float)xlo, fx1 = (float)xhi;
    const float fy0 = (float)ylo, fy1 = (float)yhi;
    const float ex = wxlo * fx0 + wxhi * fx1;
    const float ey = wylo * fy0 + wyhi * fy1;
    const float Vx = wxlo * wxhi * (fx1 - fx0) * (fx1 - fx0);
    const float Vy = wylo * wyhi * (fy1 - fy0) * (fy1 - fy0);
    const float fxh = (float)xh, fyh = (float)yh;

    float S = 0.0f, wmn = INFINITY, wmx = -INFINITY;
    for (int base = rep * 4; base < npad; base += 32) {
        float4 ga[4];
        float2 gb[4];
        #pragma unroll
        for (int k = 0; k < 4; ++k) {
            ga[k] = lsA[base + k];
            gb[k] = lsB[base + k];
        }
        #pragma unroll
        for (int k = 0; k < 4; ++k) {
            const float xx = gb[k].x, yy = gb[k].y;
            const float dxh = fxh - xx, dyh = fyh - yy;
            const bool m = dxh * dxh + dyh * dyh < 400.0f;
            const float dx = ex - xx, dy = ey - yy;
            float q = dx * (ga[k].x * dx + ga[k].y * dy) + ga[k].z * dy * dy;
            float bil = -(q + ga[k].x * Vx + ga[k].z * Vy);
            bil = fminf(fmaxf(bil, -20.0f), 0.0f);
            bil = m ? bil : -1e9f;          // exp flushes to +0
            float w = ga[k].w * __expf(bil);
            S += w; wmn = fminf(wmn, w); wmx = fmaxf(wmx, w);
        }
    }
    if (rep > 0) { pS[rep - 1][lane] = S; pMn[rep - 1][lane] = wmn; pMx[rep - 1][lane] = wmx; }
    __syncthreads();
    if (rep == 0) {
        #pragma unroll
        for (int k = 0; k < 7; ++k) {
            S += pS[k][lane];
            wmn = fminf(wmn, pMn[k][lane]);
            wmx = fmaxf(wmx, pMx[k][lane]);
        }
        if (len < 512) { wmn = fminf(wmn, 0.0f); wmx = fmaxf(wmx, 0.0f); }
        float dmv = 0.5f * (S - 512.0f * wmn) / (wmx - wmn + 1e-6f) + S / (S + 1e-6f);
        dm[(v * 224 + yo) * 224 + xo] = dmv;
    }
}

// Fused: d1 = where(d, blur(d)); d2 = where(d1, blur(d1)); out = d2;
// per-block partial (sum, sumsq) -> partials[bid].  Tile 16x16 + halo 6.
// d1 halo outside the image is forced to 0 (exact zero-pad semantics).
__global__ __launch_bounds__(256) void blur2_stats_kernel(
    const float* __restrict__ in, float* __restrict__ out,
    float2* __restrict__ partials) {
    __shared__ float A[28 * 29];
    __shared__ float T[28 * 29];
    __shared__ float r1[4], r2[4];
    const int v = blockIdx.z;
    const int tx0 = blockIdx.x * 16, ty0 = blockIdx.y * 16;
    const int tid = threadIdx.x;
    const float kw[7] = {0.00443305f, 0.05400558f, 0.24203623f, 0.39905030f,
                         0.24203623f, 0.05400558f, 0.00443305f};
    const float* __restrict__ chan = in + v * 224 * 224;

    for (int idx = tid; idx < 28 * 28; idx += 256) {
        int rr = idx / 28, c = idx % 28;
        int gyy = ty0 - 6 + rr, gxx = tx0 - 6 + c;
        float val = 0.0f;
        if (gyy >= 0 && gyy < 224 && gxx >= 0 && gxx < 224) val = chan[gyy * 224 + gxx];
        A[rr * 29 + c] = val;
    }
    __syncthreads();
    // vertical blur of d: rows 3..24, cols 0..27
    for (int idx = tid; idx < 22 * 28; idx += 256) {
        int rr = 3 + idx / 28, c = idx % 28;
        float s = 0.0f;
        #pragma unroll
        for (int i = 0; i < 7; ++i) s += kw[i] * A[(rr - 3 + i) * 29 + c];
        T[rr * 29 + c] = s;
    }
    __syncthreads();
    // horizontal + where -> d1 (rows 3..24, cols 3..24); zero outside image
    for (int idx = tid; idx < 22 * 22; idx += 256) {
        int rr = 3 + idx / 22, c = 3 + idx % 22;
        int gyy = ty0 - 6 + rr, gxx = tx0 - 6 + c;
        float s = 0.0f;
        #pragma unroll
        for (int j = 0; j < 7; ++j) s += kw[j] * T[rr * 29 + c - 3 + j];
        float ctr = A[rr * 29 + c];
        float d1 = ctr > 1e-6f ? ctr : s;
        if (gyy < 0 || gyy > 223 || gxx < 0 || gxx > 223) d1 = 0.0f;
        A[rr * 29 + c] = d1;
    }
    __syncthreads();
    // vertical blur of d1: rows 6..21, cols 3..24
    for (int idx = tid; idx < 16 * 22; idx += 256) {
        int rr = 6 + idx / 22, c = 3 + idx % 22;
        float s = 0.0f;
        #pragma unroll
        for (int i = 0; i < 7; ++i) s += kw[i] * A[(rr - 3 + i) * 29 + c];
        T[rr * 29 + c] = s;
    }
    __syncthreads();
    float ls1 = 0.0f, ls2 = 0.0f;
    for (int idx = tid; idx < 16 * 16; idx += 256) {
        int rr = 6 + (idx >> 4), c = 6 + (idx & 15);
        float s = 0.0f;
        #pragma unroll
        for (int j = 0; j < 7; ++j) s += kw[j] * T[rr * 29 + c - 3 + j];
        float ctr = A[rr * 29 + c];
        float d2 = ctr > 1e-6f ? ctr : s;
        out[(v * 224 + ty0 + rr - 6) * 224 + (tx0 + c - 6)] = d2;
        ls1 += d2; ls2 += d2 * d2;
    }
    #pragma unroll
    for (int o = 32; o >= 1; o >>= 1) {
        ls1 += __shfl_xor(ls1, o);
        ls2 += __shfl_xor(ls2, o);
    }
    if ((tid & 63) == 0) { r1[tid >> 6] = ls1; r2[tid >> 6] = ls2; }
    __syncthreads();
    if (tid == 0) {
        float s1 = r1[0] + r1[1] + r1[2] + r1[3];
        float s2 = r2[0] + r2[1] + r2[2] + r2[3];
        partials[(blockIdx.z * 14 + blockIdx.y) * 14 + blockIdx.x] = make_float2(s1, s2);
    }
}

// Inline reduce of 588 block partials (double), then normalize in place.
__global__ __launch_bounds__(256) void normalize_kernel(
    const float2* __restrict__ partials, float* __restrict__ out) {
    __shared__ double s1[256], s2[256];
    const int tid = threadIdx.x;
    double a = 0.0, b = 0.0;
    for (int i = tid; i < 588; i += 256) {
        float2 p = partials[i];
        a += (double)p.x; b += (double)p.y;
    }
    s1[tid] = a; s2[tid] = b;
    __syncthreads();
    for (int s = 128; s >= 1; s >>= 1) {
        if (tid < s) { s1[tid] += s1[tid + s]; s2[tid] += s2[tid + s]; }
        __syncthreads();
    }
    const double M = 150528.0;
    double mean = s1[0] / M;
    double var = (s2[0] - M * mean * mean) / (M - 1.0);
    double sd = sqrt(var > 0.0 ? var : 0.0);
    const int idx = blockIdx.x * 256 + tid;
    if (idx < 3 * 224 * 224)
        out[idx] = (out[idx] - (float)mean) / ((float)sd + 1e-6f);
}

extern "C" void kernel_launch(void* const* d_in, const int* in_sizes, int n_in,
                              void* d_out, int out_size, void* d_ws, size_t ws_size,
                              hipStream_t stream) {
    const float* position   = (const float*)d_in[0];  // (1,512,3)
    const float* cov3d      = (const float*)d_in[1];  // (1,512,3,3)
    const float* opacity    = (const float*)d_in[2];  // (1,512)
    const float* importance = (const float*)d_in[3];  // (1,1000)
    float* out = (float*)d_out;                       // (1,3,224,224)

    float* dmA       = (float*)d_ws;                  // 150528 floats
    float2* partials = (float2*)((float*)d_ws + 150528);  // 588 float2

    hipLaunchKernelGGL(splat_fused_kernel, dim3(28, 28, 3), dim3(512), 0, stream,
                       position, cov3d, opacity, importance, dmA);
    hipLaunchKernelGGL(blur2_stats_kernel, dim3(14, 14, 3), dim3(256), 0, stream,
                       dmA, out, partials);
    hipLaunchKernelGGL(normalize_kernel, dim3(588), dim3(256), 0, stream,
                       partials, out);
}

// Round 7
// 89.805 us; speedup vs baseline: 2.3294x; 1.0586x over previous
//
#include <hip/hip_runtime.h>
#include <math.h>

// ---------------------------------------------------------------------------
// FullGaussianProjector: B=1, N=512, 3 views, 224x224 out, half-res 112x112.
// 3 launches:
//   splat_fused: per-block redundant setup -> tile cull/compact (SoA f32)
//                -> 8 waves x 1/8-list chunks, each lane owns a 2x2 px quad
//                (one half-res pixel) -> LDS float4 merge -> dm.
//   blur2_stats: 2x (separable blur + where) in LDS + per-block partial sums
//   normalize:   inline reduce of 588 partials -> (x-mean)/(sd+eps)
// Closed forms:
//   sum_n nw = 0.5*(S - N*wmin)/(wmax-wmin+eps) + S/(S+eps)
//   bilinear(quadratic) = quad(Ex,Ey) - (a*Vx + c*Vy)
// NOTE (R5 lesson): a,2b,c,op must stay f32 — bf16 on the exponent path
// fails absmax through the (wmax-wmin) normalization.
// ---------------------------------------------------------------------------

__device__ __forceinline__ float wave_min(float v) {
    #pragma unroll
    for (int o = 32; o >= 1; o >>= 1) v = fminf(v, __shfl_xor(v, o));
    return v;
}

// Block: 512 threads (8 waves), tile 16x16 full-res px (8x8 quads), grid (14,14,3).
__global__ __launch_bounds__(512) void splat_fused_kernel(
    const float* __restrict__ position, const float* __restrict__ cov3d,
    const float* __restrict__ opacity, const float* __restrict__ importance,
    float* __restrict__ dm) {
    __shared__ float4 lsA[512];        // a, 2b, c, op
    __shared__ float2 lsB[512];        // gx, gy
    __shared__ float red[8 * 6];       // cross-wave min/max scratch
    __shared__ float4 pS[7][64], pMn[7][64], pMx[7][64];
    __shared__ int cnt;
    const int v = blockIdx.z;
    const int tx0 = blockIdx.x * 16, ty0 = blockIdx.y * 16;
    const int tid = threadIdx.x;
    const int lane = tid & 63, wave = tid >> 6;

    // ---------------- setup (1 gaussian per thread) ----------------
    const int n = tid;
    const float p0 = position[n * 3 + 0];
    const float p1 = position[n * 3 + 1];
    const float p2 = position[n * 3 + 2];
    const float opimp = opacity[n] * fminf(fmaxf(importance[n], 0.5f), 2.0f);

    {
        float vals[6] = {p0, -p0, p1, -p1, p2, -p2};
        #pragma unroll
        for (int k = 0; k < 6; ++k) {
            float r = wave_min(vals[k]);
            if (lane == 0) red[wave * 6 + k] = r;
        }
    }
    __syncthreads();
    float mn6[6];
    #pragma unroll
    for (int k = 0; k < 6; ++k) {
        float r = red[k];
        #pragma unroll
        for (int w = 1; w < 8; ++w) r = fminf(r, red[w * 6 + k]);
        mn6[k] = r;
    }
    const float pmn[3] = {mn6[0], mn6[2], mn6[4]};
    const float pmx[3] = {-mn6[1], -mn6[3], -mn6[5]};

    float c00 = cov3d[n * 9 + 0], c01 = cov3d[n * 9 + 1], c02 = cov3d[n * 9 + 2];
    float c10 = cov3d[n * 9 + 3], c11 = cov3d[n * 9 + 4], c12 = cov3d[n * 9 + 5];
    float c20 = cov3d[n * 9 + 6], c21 = cov3d[n * 9 + 7], c22 = cov3d[n * 9 + 8];
    for (int vv = 0; vv <= v; ++vv) {
        float s01 = 0.5f * (c01 + c10);
        float s02 = 0.5f * (c02 + c20);
        float s12 = 0.5f * (c12 + c21);
        float s00 = c00 + 1e-6f;
        float s11 = c11 + 1e-6f;
        float s22 = c22 + 1e-6f;
        float nrm = sqrtf(s00 * s00 + s11 * s11 + s22 * s22 +
                          2.0f * (s01 * s01 + s02 * s02 + s12 * s12));
        float inv = 1.0f / (nrm + 1e-6f);
        c00 = s00 * inv; c11 = s11 * inv; c22 = s22 * inv;
        c01 = s01 * inv; c10 = c01; c02 = s02 * inv; c20 = c02;
        c12 = s12 * inv; c21 = c12;
    }
    float cof00 = c11 * c22 - c12 * c12;
    float cof01 = c02 * c12 - c01 * c22;
    float cof02 = c01 * c12 - c02 * c11;
    float det = c00 * cof00 + c01 * cof01 + c02 * cof02;
    float idet = 1.0f / det;
    float i00 = cof00 * idet;
    float i01 = cof01 * idet;
    float i02 = cof02 * idet;
    float i11 = (c00 * c22 - c02 * c02) * idet;
    float i12 = (c02 * c01 - c00 * c12) * idet;
    float i22 = (c00 * c11 - c01 * c01) * idet;

    float Aa, Ab, Ac, prx, pry;
    int ix, iy;
    if (v == 0)      { Aa = i00; Ab = i01; Ac = i11; prx = p0; pry = p1; ix = 0; iy = 1; }
    else if (v == 1) { Aa = i00; Ab = i02; Ac = i22; prx = p0; pry = p2; ix = 0; iy = 2; }
    else             { Aa = i22; Ab = i12; Ac = i11; prx = p2; pry = p1; ix = 2; iy = 1; }
    Aa += 1e-10f;
    Ac += 1e-10f;

    float mnx = pmn[ix], mxx = pmx[ix], mny = pmn[iy], mxy = pmx[iy];
    float rngx = mxx - mnx + 1e-6f;
    float mnx2 = mnx - 0.5f * rngx;
    float mxx2 = mxx + 0.5f * rngx;
    rngx = mxx2 - mnx2 + 1e-6f;
    float rngy = mxy - mny + 1e-6f;
    float mny2 = mny - 0.5f * rngy;
    float mxy2 = mxy + 0.5f * rngy;
    rngy = mxy2 - mny2 + 1e-6f;
    float gx = fminf(fmaxf((prx - mnx2) / rngx * 111.0f, 0.0f), 111.0f);
    float gy = fminf(fmaxf((pry - mny2) / rngy * 111.0f, 0.0f), 111.0f);

    // ---------------- cull + compact into LDS (SoA f32) ----------------
    if (tid == 0) cnt = 0;
    __syncthreads();
    {
        const float bx0 = (float)(tx0 >> 1), bx1 = (float)((tx0 + 15) >> 1);
        const float by0 = (float)(ty0 >> 1), by1 = (float)((ty0 + 15) >> 1);
        float dx = fmaxf(fmaxf(bx0 - gx, gx - bx1), 0.0f);
        float dy = fmaxf(fmaxf(by0 - gy, gy - by1), 0.0f);
        bool pass = (dx * dx + dy * dy) < 400.01f;  // conservative superset
        unsigned long long m = __ballot(pass);
        int base = 0;
        if (lane == 0) base = atomicAdd(&cnt, __popcll(m));
        base = __shfl(base, 0);
        if (pass) {
            int slot = base + __popcll(m & ((1ull << lane) - 1ull));
            lsA[slot] = make_float4(Aa, 2.0f * Ab, Ac, opimp);
            lsB[slot] = make_float2(gx, gy);
        }
    }
    __syncthreads();
    const int len = cnt;

    // quad owned by this lane: half-res pixel (xh, yh)
    const int qx = lane & 7, qy = lane >> 3;
    const int xh = (tx0 >> 1) + qx;
    const int yh = (ty0 >> 1) + qy;

    if (len == 0) {  // uniform branch: whole block exits
        if (wave == 0) {
            #pragma unroll
            for (int py = 0; py < 2; ++py)
                #pragma unroll
                for (int px = 0; px < 2; ++px)
                    dm[(v * 224 + ty0 + 2 * qy + py) * 224 + tx0 + 2 * qx + px] = 0.0f;
        }
        return;
    }

    const int npad = (len + 15) & ~15;
    if (tid < npad - len) {  // no-op pad gaussians (mask always fails -> w=0)
        lsA[len + tid] = make_float4(1.0f, 0.0f, 1.0f, 0.0f);
        lsB[len + tid] = make_float2(1e9f, 1e9f);
    }
    __syncthreads();

    // per-parity constants (generic formula, preserves edge clamping exactly)
    float exA[2], eyA[2], VxA[2], VyA[2];
    #pragma unroll
    for (int p = 0; p < 2; ++p) {
        int xlo = xh - 1 + p; int xhi = min(xlo + 1, 111); xlo = max(xlo, 0);
        float wlo = p ? 0.75f : 0.25f, whi = 1.0f - wlo;
        exA[p] = wlo * (float)xlo + whi * (float)xhi;
        VxA[p] = wlo * whi * (float)(xhi - xlo) * (float)(xhi - xlo);
        int ylo = yh - 1 + p; int yhi2 = min(ylo + 1, 111); ylo = max(ylo, 0);
        eyA[p] = wlo * (float)ylo + whi * (float)yhi2;
        VyA[p] = wlo * whi * (float)(yhi2 - ylo) * (float)(yhi2 - ylo);
    }
    const float fxh = (float)xh, fyh = (float)yh;

    // ---------------- list chunk for this wave, quad eval ----------------
    const int chunk = npad >> 3;           // multiple of 2
    const int cbeg = wave * chunk, cend = cbeg + chunk;

    float S00 = 0.f, S01 = 0.f, S10 = 0.f, S11 = 0.f;
    float mn00 = INFINITY, mn01 = INFINITY, mn10 = INFINITY, mn11 = INFINITY;
    float mx00 = -INFINITY, mx01 = -INFINITY, mx10 = -INFINITY, mx11 = -INFINITY;

    for (int i = cbeg; i < cend; i += 2) {
        float4 gA0 = lsA[i], gA1 = lsA[i + 1];
        float2 gB0 = lsB[i], gB1 = lsB[i + 1];
        #pragma unroll
        for (int u = 0; u < 2; ++u) {
            const float4 gA = u ? gA1 : gA0;
            const float2 gB = u ? gB1 : gB0;
            const float a = gA.x, b2 = gA.y, c = gA.z, op = gA.w;
            const float xx = gB.x, yy = gB.y;
            const float dxh = fxh - xx, dyh = fyh - yy;
            const bool inside = dxh * dxh + dyh * dyh < 400.0f;
            const float dx0 = exA[0] - xx, dx1 = exA[1] - xx;
            const float dy0 = eyA[0] - yy, dy1 = eyA[1] - yy;
            const float adx0 = a * dx0, adx1 = a * dx1;
            const float bdy0 = b2 * dy0, bdy1 = b2 * dy1;
            const float cdy0 = c * dy0 * dy0, cdy1 = c * dy1 * dy1;
            const float ax0 = a * VxA[0], ax1 = a * VxA[1];
            const float cy0 = c * VyA[0], cy1 = c * VyA[1];
            #pragma unroll
            for (int py = 0; py < 2; ++py) {
                const float dyp  = py ? dy1 : dy0;
                const float bdyp = py ? bdy1 : bdy0;
                const float cdyp = py ? cdy1 : cdy0;
                const float cyp  = py ? cy1 : cy0;
                #pragma unroll
                for (int px = 0; px < 2; ++px) {
                    const float dxp  = px ? dx1 : dx0;
                    const float adxp = px ? adx1 : adx0;
                    const float axp  = px ? ax1 : ax0;
                    float q = dxp * (adxp + bdyp) + cdyp;
                    float bil = -((q + axp) + cyp);
                    bil = fminf(fmaxf(bil, -20.0f), 0.0f);
                    bil = inside ? bil : -1e9f;   // exp flushes to +0
                    float w = op * __expf(bil);
                    if (py == 0 && px == 0) { S00 += w; mn00 = fminf(mn00, w); mx00 = fmaxf(mx00, w); }
                    if (py == 0 && px == 1) { S01 += w; mn01 = fminf(mn01, w); mx01 = fmaxf(mx01, w); }
                    if (py == 1 && px == 0) { S10 += w; mn10 = fminf(mn10, w); mx10 = fmaxf(mx10, w); }
                    if (py == 1 && px == 1) { S11 += w; mn11 = fminf(mn11, w); mx11 = fmaxf(mx11, w); }
                }
            }
        }
    }
    if (wave > 0) {
        pS[wave - 1][lane]  = make_float4(S00, S01, S10, S11);
        pMn[wave - 1][lane] = make_float4(mn00, mn01, mn10, mn11);
        pMx[wave - 1][lane] = make_float4(mx00, mx01, mx10, mx11);
    }
    __syncthreads();
    if (wave == 0) {
        #pragma unroll
        for (int k = 0; k < 7; ++k) {
            float4 s = pS[k][lane], m = pMn[k][lane], M = pMx[k][lane];
            S00 += s.x; S01 += s.y; S10 += s.z; S11 += s.w;
            mn00 = fminf(mn00, m.x); mn01 = fminf(mn01, m.y);
            mn10 = fminf(mn10, m.z); mn11 = fminf(mn11, m.w);
            mx00 = fmaxf(mx00, M.x); mx01 = fmaxf(mx01, M.y);
            mx10 = fmaxf(mx10, M.z); mx11 = fmaxf(mx11, M.w);
        }
        if (len < 512) {
            mn00 = fminf(mn00, 0.f); mn01 = fminf(mn01, 0.f);
            mn10 = fminf(mn10, 0.f); mn11 = fminf(mn11, 0.f);
            mx00 = fmaxf(mx00, 0.f); mx01 = fmaxf(mx01, 0.f);
            mx10 = fmaxf(mx10, 0.f); mx11 = fmaxf(mx11, 0.f);
        }
        float S4[4]  = {S00, S01, S10, S11};
        float mn4[4] = {mn00, mn01, mn10, mn11};
        float mx4[4] = {mx00, mx01, mx10, mx11};
        #pragma unroll
        for (int pp = 0; pp < 4; ++pp) {
            float S = S4[pp];
            float dmv = 0.5f * (S - 512.0f * mn4[pp]) / (mx4[pp] - mn4[pp] + 1e-6f)
                      + S / (S + 1e-6f);
            const int py = pp >> 1, px = pp & 1;
            dm[(v * 224 + ty0 + 2 * qy + py) * 224 + tx0 + 2 * qx + px] = dmv;
        }
    }
}

// Fused: d1 = where(d, blur(d)); d2 = where(d1, blur(d1)); out = d2;
// per-block partial (sum, sumsq) -> partials[bid].  Tile 16x16 + halo 6.
// d1 halo outside the image is forced to 0 (exact zero-pad semantics).
__global__ __launch_bounds__(256) void blur2_stats_kernel(
    const float* __restrict__ in, float* __restrict__ out,
    float2* __restrict__ partials) {
    __shared__ float A[28 * 29];
    __shared__ float T[28 * 29];
    __shared__ float r1[4], r2[4];
    const int v = blockIdx.z;
    const int tx0 = blockIdx.x * 16, ty0 = blockIdx.y * 16;
    const int tid = threadIdx.x;
    const float kw[7] = {0.00443305f, 0.05400558f, 0.24203623f, 0.39905030f,
                         0.24203623f, 0.05400558f, 0.00443305f};
    const float* __restrict__ chan = in + v * 224 * 224;

    for (int idx = tid; idx < 28 * 28; idx += 256) {
        int rr = idx / 28, c = idx % 28;
        int gyy = ty0 - 6 + rr, gxx = tx0 - 6 + c;
        float val = 0.0f;
        if (gyy >= 0 && gyy < 224 && gxx >= 0 && gxx < 224) val = chan[gyy * 224 + gxx];
        A[rr * 29 + c] = val;
    }
    __syncthreads();
    for (int idx = tid; idx < 22 * 28; idx += 256) {
        int rr = 3 + idx / 28, c = idx % 28;
        float s = 0.0f;
        #pragma unroll
        for (int i = 0; i < 7; ++i) s += kw[i] * A[(rr - 3 + i) * 29 + c];
        T[rr * 29 + c] = s;
    }
    __syncthreads();
    for (int idx = tid; idx < 22 * 22; idx += 256) {
        int rr = 3 + idx / 22, c = 3 + idx % 22;
        int gyy = ty0 - 6 + rr, gxx = tx0 - 6 + c;
        float s = 0.0f;
        #pragma unroll
        for (int j = 0; j < 7; ++j) s += kw[j] * T[rr * 29 + c - 3 + j];
        float ctr = A[rr * 29 + c];
        float d1 = ctr > 1e-6f ? ctr : s;
        if (gyy < 0 || gyy > 223 || gxx < 0 || gxx > 223) d1 = 0.0f;
        A[rr * 29 + c] = d1;
    }
    __syncthreads();
    for (int idx = tid; idx < 16 * 22; idx += 256) {
        int rr = 6 + idx / 22, c = 3 + idx % 22;
        float s = 0.0f;
        #pragma unroll
        for (int i = 0; i < 7; ++i) s += kw[i] * A[(rr - 3 + i) * 29 + c];
        T[rr * 29 + c] = s;
    }
    __syncthreads();
    float ls1 = 0.0f, ls2 = 0.0f;
    for (int idx = tid; idx < 16 * 16; idx += 256) {
        int rr = 6 + (idx >> 4), c = 6 + (idx & 15);
        float s = 0.0f;
        #pragma unroll
        for (int j = 0; j < 7; ++j) s += kw[j] * T[rr * 29 + c - 3 + j];
        float ctr = A[rr * 29 + c];
        float d2 = ctr > 1e-6f ? ctr : s;
        out[(v * 224 + ty0 + rr - 6) * 224 + (tx0 + c - 6)] = d2;
        ls1 += d2; ls2 += d2 * d2;
    }
    #pragma unroll
    for (int o = 32; o >= 1; o >>= 1) {
        ls1 += __shfl_xor(ls1, o);
        ls2 += __shfl_xor(ls2, o);
    }
    if ((tid & 63) == 0) { r1[tid >> 6] = ls1; r2[tid >> 6] = ls2; }
    __syncthreads();
    if (tid == 0) {
        float s1 = r1[0] + r1[1] + r1[2] + r1[3];
        float s2 = r2[0] + r2[1] + r2[2] + r2[3];
        partials[(blockIdx.z * 14 + blockIdx.y) * 14 + blockIdx.x] = make_float2(s1, s2);
    }
}

// Inline reduce of 588 block partials (double), then normalize in place.
__global__ __launch_bounds__(256) void normalize_kernel(
    const float2* __restrict__ partials, float* __restrict__ out) {
    __shared__ double s1[256], s2[256];
    const int tid = threadIdx.x;
    double a = 0.0, b = 0.0;
    for (int i = tid; i < 588; i += 256) {
        float2 p = partials[i];
        a += (double)p.x; b += (double)p.y;
    }
    s1[tid] = a; s2[tid] = b;
    __syncthreads();
    for (int s = 128; s >= 1; s >>= 1) {
        if (tid < s) { s1[tid] += s1[tid + s]; s2[tid] += s2[tid + s]; }
        __syncthreads();
    }
    const double M = 150528.0;
    double mean = s1[0] / M;
    double var = (s2[0] - M * mean * mean) / (M - 1.0);
    double sd = sqrt(var > 0.0 ? var : 0.0);
    const int idx = blockIdx.x * 256 + tid;
    if (idx < 3 * 224 * 224)
        out[idx] = (out[idx] - (float)mean) / ((float)sd + 1e-6f);
}

extern "C" void kernel_launch(void* const* d_in, const int* in_sizes, int n_in,
                              void* d_out, int out_size, void* d_ws, size_t ws_size,
                              hipStream_t stream) {
    const float* position   = (const float*)d_in[0];  // (1,512,3)
    const float* cov3d      = (const float*)d_in[1];  // (1,512,3,3)
    const float* opacity    = (const float*)d_in[2];  // (1,512)
    const float* importance = (const float*)d_in[3];  // (1,1000)
    float* out = (float*)d_out;                       // (1,3,224,224)

    float* dmA       = (float*)d_ws;                  // 150528 floats
    float2* partials = (float2*)((float*)d_ws + 150528);  // 588 float2

    hipLaunchKernelGGL(splat_fused_kernel, dim3(14, 14, 3), dim3(512), 0, stream,
                       position, cov3d, opacity, importance, dmA);
    hipLaunchKernelGGL(blur2_stats_kernel, dim3(14, 14, 3), dim3(256), 0, stream,
                       dmA, out, partials);
    hipLaunchKernelGGL(normalize_kernel, dim3(588), dim3(256), 0, stream,
                       partials, out);
}